// Round 1
// baseline (7111.051 us; speedup 1.0000x reference)
//
#include <hip/hip_runtime.h>
#include <hip/hip_bf16.h>

// Sizes
#define BATCH 256
#define UNITS 1024
#define FEATS 128
#define TWARM 256
#define TFC   128
#define NG    4096          // 4*UNITS
#define KW    1152          // UNITS + FEATS (warmup K)
#define KF    1024          // forecast K
#define NF    4224          // NG + FEATS (forecast N)

typedef __attribute__((ext_vector_type(8))) short bf16x8;
typedef __attribute__((ext_vector_type(4))) float f32x4;

__device__ __forceinline__ float sigf(float x) { return 1.0f / (1.0f + __expf(-x)); }
__device__ __forceinline__ float tanh_fast(float x) { return 2.0f / (1.0f + __expf(-2.0f * x)) - 1.0f; }

// ---------- precompute kernels ----------

__global__ void cvt_bf16(const float* __restrict__ in, __hip_bfloat16* __restrict__ out, int n) {
    int i = (blockIdx.x * blockDim.x + threadIdx.x) * 4;
    if (i >= n) return;
    float4 v = *(const float4*)(in + i);
    union { ushort4 u4; __hip_bfloat16 h[4]; } pk;
    pk.h[0] = __float2bfloat16(v.x);
    pk.h[1] = __float2bfloat16(v.y);
    pk.h[2] = __float2bfloat16(v.z);
    pk.h[3] = __float2bfloat16(v.w);
    *(ushort4*)(out + i) = pk.u4;
}

// Wc[j][k], j in [0,4096): reordered gate col j=4u+g -> orig col g*1024+u; k over [W_h rows; W_i rows]
__global__ void build_wc(const float* __restrict__ W_h, const float* __restrict__ W_i,
                         __hip_bfloat16* __restrict__ Wc) {
    int idx = blockIdx.x * 256 + threadIdx.x;   // 4096*1152
    int j = idx / KW, k = idx % KW;
    int u = j >> 2, g = j & 3;
    int col = g * UNITS + u;
    float v = (k < UNITS) ? W_h[k * NG + col] : W_i[(k - UNITS) * NG + col];
    Wc[idx] = __float2bfloat16(v);
}

// Wf[j][k], j<4096: W_h[k][col] + sum_q W_d[k][q]*W_i[q][col]; j>=4096: W_d[k][j-4096]
__global__ void build_wf(const float* __restrict__ W_h, const float* __restrict__ W_i,
                         const float* __restrict__ W_d, __hip_bfloat16* __restrict__ Wf) {
    int idx = blockIdx.x * 256 + threadIdx.x;   // 4224*1024
    int j = idx >> 10, k = idx & 1023;
    float v;
    if (j < NG) {
        int u = j >> 2, g = j & 3;
        int col = g * UNITS + u;
        v = W_h[k * NG + col];
        for (int q = 0; q < FEATS; ++q) v += W_d[k * FEATS + q] * W_i[q * NG + col];
    } else {
        v = W_d[k * FEATS + (j - NG)];
    }
    Wf[idx] = __float2bfloat16(v);
}

__global__ void build_bias(const float* __restrict__ b, const float* __restrict__ b_d,
                           const float* __restrict__ W_i, float* __restrict__ bias_r,
                           float* __restrict__ bias_f) {
    int j = blockIdx.x * 256 + threadIdx.x;
    if (j < NG) {
        int u = j >> 2, g = j & 3;
        int col = g * UNITS + u;
        float base = b[col];
        bias_r[j] = base;
        float v = base;
        for (int q = 0; q < FEATS; ++q) v += b_d[q] * W_i[q * NG + col];
        bias_f[j] = v;
    } else if (j < NF) {
        bias_f[j] = b_d[j - NG];
    }
}

// ---------- fused LSTM step ----------
// Grid: (4 batch-tiles, n col-tiles of 64). Block 256 = 4 waves (2x2 of 32x32).
// Computes z-tile = [h|x] @ Wt^T for 64 batches x 64 cols (reordered i,f,g,o per unit),
// then applies cell update in-place (gate tiles) or writes p (p tiles, forecast only).
__global__ __launch_bounds__(256) void step_kernel(
    const __hip_bfloat16* __restrict__ Wt,    // [N][K] bf16
    const float* __restrict__ bias,           // [N]
    const __hip_bfloat16* __restrict__ h_in,  // [256][1024]
    const __hip_bfloat16* __restrict__ xin,   // [256][x_stride] slice base (or null)
    float* __restrict__ c,                    // [256][1024]
    __hip_bfloat16* __restrict__ h_out,       // [256][1024]
    float* __restrict__ p_out,                // d_out + t*128 (or null), row stride 16384
    int K, int x_stride)
{
    __shared__ __hip_bfloat16 Al[64][40];
    __shared__ __hip_bfloat16 Bl[64][40];
    __shared__ float Zl[64][68];

    const int tid = threadIdx.x;
    const int b0 = blockIdx.x * 64;
    const int n0 = blockIdx.y * 64;
    const int wave = tid >> 6, lane = tid & 63;
    const int wr = (wave >> 1) * 32, wc = (wave & 1) * 32;
    const int lr = lane & 15, lk = (lane >> 4) * 8;

    const int r  = tid >> 2;          // staging row 0..63
    const int ck = (tid & 3) * 8;     // staging k-chunk

    f32x4 acc[2][2] = {{{0.f,0.f,0.f,0.f},{0.f,0.f,0.f,0.f}},
                       {{0.f,0.f,0.f,0.f},{0.f,0.f,0.f,0.f}}};

    const int nk = K >> 5;
    for (int kk = 0; kk < nk; ++kk) {
        const int k0 = kk << 5;
        // stage A (h rows, then x rows)
        const __hip_bfloat16* asrc = (k0 < UNITS)
            ? (h_in + (size_t)(b0 + r) * UNITS + k0 + ck)
            : (xin  + (size_t)(b0 + r) * x_stride + (k0 - UNITS) + ck);
        *(int4*)(&Al[r][ck]) = *(const int4*)asrc;
        // stage B (weight rows = output cols)
        *(int4*)(&Bl[r][ck]) = *(const int4*)(Wt + (size_t)(n0 + r) * K + k0 + ck);
        __syncthreads();

        bf16x8 a0 = *(const bf16x8*)(&Al[wr + lr][lk]);
        bf16x8 a1 = *(const bf16x8*)(&Al[wr + lr + 16][lk]);
        bf16x8 bA = *(const bf16x8*)(&Bl[wc + lr][lk]);
        bf16x8 bB = *(const bf16x8*)(&Bl[wc + lr + 16][lk]);
        acc[0][0] = __builtin_amdgcn_mfma_f32_16x16x32_bf16(a0, bA, acc[0][0], 0, 0, 0);
        acc[0][1] = __builtin_amdgcn_mfma_f32_16x16x32_bf16(a0, bB, acc[0][1], 0, 0, 0);
        acc[1][0] = __builtin_amdgcn_mfma_f32_16x16x32_bf16(a1, bA, acc[1][0], 0, 0, 0);
        acc[1][1] = __builtin_amdgcn_mfma_f32_16x16x32_bf16(a1, bB, acc[1][1], 0, 0, 0);
        __syncthreads();
    }

    // z (+bias) to LDS
    #pragma unroll
    for (int rf = 0; rf < 2; ++rf)
        #pragma unroll
        for (int cf = 0; cf < 2; ++cf)
            #pragma unroll
            for (int i = 0; i < 4; ++i) {
                int m = wr + rf * 16 + (lane >> 4) * 4 + i;
                int n = wc + cf * 16 + lr;
                Zl[m][n] = acc[rf][cf][i] + bias[n0 + n];
            }
    __syncthreads();

    if (n0 < NG) {
        // gate tile: 16 units x 64 batches -> cell update
        const int u0 = n0 >> 2;
        for (int it = tid; it < 1024; it += 256) {
            int bl = it >> 4, ul = it & 15;
            float4 z = *(const float4*)(&Zl[bl][ul * 4]);
            size_t gidx = (size_t)(b0 + bl) * UNITS + u0 + ul;
            float cv = c[gidx];
            float ig = sigf(z.x), fg = sigf(z.y), gg = tanh_fast(z.z), og = sigf(z.w);
            float cn = fg * cv + ig * gg;
            c[gidx] = cn;
            h_out[gidx] = __float2bfloat16(og * tanh_fast(cn));
        }
    } else if (p_out) {
        // prediction tile: write p = h@W_d + b_d to output
        const int f0 = n0 - NG;
        for (int it = tid; it < 4096; it += 256) {
            int bl = it >> 6, fl = it & 63;
            p_out[(size_t)(b0 + bl) * (TFC * FEATS) + f0 + fl] = Zl[bl][fl];
        }
    }
}

// ---------- launcher ----------

extern "C" void kernel_launch(void* const* d_in, const int* in_sizes, int n_in,
                              void* d_out, int out_size, void* d_ws, size_t ws_size,
                              hipStream_t stream) {
    const float* inputs = (const float*)d_in[0];
    const float* W_i    = (const float*)d_in[1];
    const float* W_h    = (const float*)d_in[2];
    const float* b      = (const float*)d_in[3];
    const float* W_d    = (const float*)d_in[4];
    const float* b_d    = (const float*)d_in[5];
    float* out = (float*)d_out;

    char* ws = (char*)d_ws;
    // layout (bytes)
    __hip_bfloat16* x_bf   = (__hip_bfloat16*)(ws);                 // 16,777,216
    __hip_bfloat16* Wc     = (__hip_bfloat16*)(ws + 16777216);      //  9,437,184
    __hip_bfloat16* Wf     = (__hip_bfloat16*)(ws + 26214400);      //  8,650,752
    float*          bias_r = (float*)(ws + 34865152);               //     16,384
    float*          bias_f = (float*)(ws + 34881536);               //     16,896
    __hip_bfloat16* hbuf0  = (__hip_bfloat16*)(ws + 34898432);      //    524,288
    __hip_bfloat16* hbuf1  = (__hip_bfloat16*)(ws + 35422720);      //    524,288
    float*          cbuf   = (float*)(ws + 35947008);               //  1,048,576
    __hip_bfloat16* hb[2] = { hbuf0, hbuf1 };

    hipMemsetAsync(hbuf0, 0, 524288, stream);
    hipMemsetAsync(cbuf, 0, 1048576, stream);

    cvt_bf16<<<8192, 256, 0, stream>>>(inputs, x_bf, BATCH * TWARM * FEATS);
    build_wc<<<(NG * KW) / 256, 256, 0, stream>>>(W_h, W_i, Wc);
    build_wf<<<(NF * KF) / 256, 256, 0, stream>>>(W_h, W_i, W_d, Wf);
    build_bias<<<(NF + 255) / 256, 256, 0, stream>>>(b, b_d, W_i, bias_r, bias_f);

    // warmup: z = [h | x_t] @ [W_h; W_i]^T + b
    for (int t = 0; t < TWARM; ++t) {
        step_kernel<<<dim3(4, 64), 256, 0, stream>>>(
            Wc, bias_r, hb[t & 1], x_bf + (size_t)t * FEATS,
            cbuf, hb[(t + 1) & 1], nullptr, KW, TWARM * FEATS);
    }
    // forecast: z = h @ (W_h + W_d W_i)^T + (b + b_d W_i); p = h @ W_d + b_d -> out[:, t, :]
    for (int t = 0; t < TFC; ++t) {
        step_kernel<<<dim3(4, 66), 256, 0, stream>>>(
            Wf, bias_f, hb[t & 1], nullptr,
            cbuf, hb[(t + 1) & 1], out + (size_t)t * FEATS, KF, 0);
    }
}

// Round 2
// 5911.535 us; speedup vs baseline: 1.2029x; 1.2029x over previous
//
#include <hip/hip_runtime.h>
#include <hip/hip_bf16.h>

// Sizes
#define BATCH 256
#define UNITS 1024
#define FEATS 128
#define TWARM 256
#define TFC   128
#define NG    4096          // 4*UNITS
#define KW    1152          // UNITS + FEATS (warmup K)
#define KF    1024          // forecast K
#define NF    4224          // NG + FEATS (forecast N)

typedef __attribute__((ext_vector_type(8))) short bf16x8;
typedef __attribute__((ext_vector_type(4))) float f32x4;

typedef __attribute__((address_space(3))) char lds_char;
typedef __attribute__((address_space(1))) const char glb_char;

__device__ __forceinline__ void gload_lds16(const void* g, void* l) {
    __builtin_amdgcn_global_load_lds((glb_char*)g, (lds_char*)l, 16, 0, 0);
}

#define CFENCE asm volatile("" ::: "memory")
#define SBAR   do { CFENCE; __builtin_amdgcn_s_barrier(); CFENCE; } while (0)
#define WAIT_VM(N) asm volatile("s_waitcnt vmcnt(" #N ")" ::: "memory")

__device__ __forceinline__ float sigf(float x) { return 1.0f / (1.0f + __expf(-x)); }
__device__ __forceinline__ float tanh_fast(float x) { return 2.0f / (1.0f + __expf(-2.0f * x)) - 1.0f; }

// ---------- precompute kernels ----------

__global__ void cvt_bf16(const float* __restrict__ in, __hip_bfloat16* __restrict__ out, int n) {
    int i = (blockIdx.x * blockDim.x + threadIdx.x) * 4;
    if (i >= n) return;
    float4 v = *(const float4*)(in + i);
    union { ushort4 u4; __hip_bfloat16 h[4]; } pk;
    pk.h[0] = __float2bfloat16(v.x);
    pk.h[1] = __float2bfloat16(v.y);
    pk.h[2] = __float2bfloat16(v.z);
    pk.h[3] = __float2bfloat16(v.w);
    *(ushort4*)(out + i) = pk.u4;
}

// Wc[j][k], j in [0,4096): reordered gate col j=4u+g -> orig col g*1024+u; k over [W_h rows; W_i rows]
__global__ void build_wc(const float* __restrict__ W_h, const float* __restrict__ W_i,
                         __hip_bfloat16* __restrict__ Wc) {
    int idx = blockIdx.x * 256 + threadIdx.x;   // 4096*1152
    int j = idx / KW, k = idx % KW;
    int u = j >> 2, g = j & 3;
    int col = g * UNITS + u;
    float v = (k < UNITS) ? W_h[k * NG + col] : W_i[(k - UNITS) * NG + col];
    Wc[idx] = __float2bfloat16(v);
}

// Wf[j][k], j<4096: W_h[k][col] + sum_q W_d[k][q]*W_i[q][col]; j>=4096: W_d[k][j-4096]
__global__ void build_wf(const float* __restrict__ W_h, const float* __restrict__ W_i,
                         const float* __restrict__ W_d, __hip_bfloat16* __restrict__ Wf) {
    int idx = blockIdx.x * 256 + threadIdx.x;   // 4224*1024
    int j = idx >> 10, k = idx & 1023;
    float v;
    if (j < NG) {
        int u = j >> 2, g = j & 3;
        int col = g * UNITS + u;
        v = W_h[k * NG + col];
        for (int q = 0; q < FEATS; ++q) v += W_d[k * FEATS + q] * W_i[q * NG + col];
    } else {
        v = W_d[k * FEATS + (j - NG)];
    }
    Wf[idx] = __float2bfloat16(v);
}

__global__ void build_bias(const float* __restrict__ b, const float* __restrict__ b_d,
                           const float* __restrict__ W_i, float* __restrict__ bias_r,
                           float* __restrict__ bias_f) {
    int j = blockIdx.x * 256 + threadIdx.x;
    if (j < NG) {
        int u = j >> 2, g = j & 3;
        int col = g * UNITS + u;
        float base = b[col];
        bias_r[j] = base;
        float v = base;
        for (int q = 0; q < FEATS; ++q) v += b_d[q] * W_i[q * NG + col];
        bias_f[j] = v;
    } else if (j < NF) {
        bias_f[j] = b_d[j - NG];
    }
}

// ---------- fused LSTM step ----------
// Grid: (4 batch-tiles, n col-tiles of 64). Block 256 = 4 waves (2x2 of 32x32).
// Double-buffered global_load_lds prefetch (BK=64), counted vmcnt, raw s_barrier.
// LDS linear [64][64] bf16; bank conflicts fixed via XOR-chunk swizzle applied on
// BOTH sides: inverse-swizzled global source addresses + swizzled ds_read addrs.
__global__ __launch_bounds__(256) void step_kernel(
    const __hip_bfloat16* __restrict__ Wt,    // [N][K] bf16
    const float* __restrict__ bias,           // [N]
    const __hip_bfloat16* __restrict__ h_in,  // [256][1024]
    const __hip_bfloat16* __restrict__ xin,   // [256][x_stride] slice base (or null)
    float* __restrict__ c,                    // [256][1024]
    __hip_bfloat16* __restrict__ h_out,       // [256][1024]
    float* __restrict__ p_out,                // d_out + t*128 (or null), row stride 16384
    int K, int x_stride)
{
    __shared__ __hip_bfloat16 Al[2][64 * 64];
    __shared__ __hip_bfloat16 Bl[2][64 * 64];
    __shared__ float Zl[64][68];

    const int tid = threadIdx.x;
    const int b0 = blockIdx.x * 64;
    const int n0 = blockIdx.y * 64;
    const int wave = tid >> 6, lane = tid & 63;
    const int wr = (wave >> 1) * 32, wc = (wave & 1) * 32;
    const int lr = lane & 15, lq = lane >> 4;

    // staging geometry: each wave issues 2 A-loads + 2 B-loads of 1KB (8 rows x 128B)
    const int l8 = lane >> 3;                 // row within 8-row group
    const int cb = lane & 7;                  // 16B chunk within row
    const int gsw = (cb ^ l8) << 3;           // inverse-swizzled element offset in window

    auto stage = [&](int buf, int k0) {
        #pragma unroll
        for (int l = 0; l < 2; ++l) {
            const int rt = wave * 16 + l * 8;         // wave-uniform row base
            const int row = rt + l8;                  // this lane's tile row
            const __hip_bfloat16* srcA;
            if (k0 < UNITS)
                srcA = h_in + (size_t)(b0 + row) * UNITS + k0 + gsw;
            else
                srcA = xin + (size_t)(b0 + row) * x_stride + (k0 - UNITS) + gsw;
            gload_lds16(srcA, &Al[buf][rt * 64]);
            gload_lds16(Wt + (size_t)(n0 + row) * K + k0 + gsw, &Bl[buf][rt * 64]);
        }
    };

    f32x4 acc[2][2] = {{{0.f,0.f,0.f,0.f},{0.f,0.f,0.f,0.f}},
                       {{0.f,0.f,0.f,0.f},{0.f,0.f,0.f,0.f}}};

    const int rA0 = wr + lr, rA1 = wr + lr + 16;
    const int rB0 = wc + lr, rB1 = wc + lr + 16;
    const int xk = lr & 7;                    // read-side swizzle key (same for all 4 rows)

    const int nk = K >> 6;
    stage(0, 0);
    for (int kk = 0; kk < nk; ++kk) {
        const int buf = kk & 1;
        if (kk + 1 < nk) {
            stage(buf ^ 1, (kk + 1) << 6);
            WAIT_VM(4);                       // current buffer's 4 loads done; next 4 in flight
        } else {
            WAIT_VM(0);
        }
        SBAR;
        #pragma unroll
        for (int ks = 0; ks < 2; ++ks) {
            const int g0 = ((ks * 4 + lq) ^ xk) << 3;
            bf16x8 a0 = *(const bf16x8*)&Al[buf][rA0 * 64 + g0];
            bf16x8 a1 = *(const bf16x8*)&Al[buf][rA1 * 64 + g0];
            bf16x8 bA = *(const bf16x8*)&Bl[buf][rB0 * 64 + g0];
            bf16x8 bB = *(const bf16x8*)&Bl[buf][rB1 * 64 + g0];
            acc[0][0] = __builtin_amdgcn_mfma_f32_16x16x32_bf16(a0, bA, acc[0][0], 0, 0, 0);
            acc[0][1] = __builtin_amdgcn_mfma_f32_16x16x32_bf16(a0, bB, acc[0][1], 0, 0, 0);
            acc[1][0] = __builtin_amdgcn_mfma_f32_16x16x32_bf16(a1, bA, acc[1][0], 0, 0, 0);
            acc[1][1] = __builtin_amdgcn_mfma_f32_16x16x32_bf16(a1, bB, acc[1][1], 0, 0, 0);
        }
        SBAR;
    }

    // z (+bias) to LDS
    #pragma unroll
    for (int rf = 0; rf < 2; ++rf)
        #pragma unroll
        for (int cf = 0; cf < 2; ++cf)
            #pragma unroll
            for (int i = 0; i < 4; ++i) {
                int m = wr + rf * 16 + lq * 4 + i;
                int n = wc + cf * 16 + lr;
                Zl[m][n] = acc[rf][cf][i] + bias[n0 + n];
            }
    __syncthreads();

    if (n0 < NG) {
        // gate tile: 16 units x 64 batches -> cell update
        const int u0 = n0 >> 2;
        for (int it = tid; it < 1024; it += 256) {
            int bl = it >> 4, ul = it & 15;
            float4 z = *(const float4*)(&Zl[bl][ul * 4]);
            size_t gidx = (size_t)(b0 + bl) * UNITS + u0 + ul;
            float cv = c[gidx];
            float ig = sigf(z.x), fg = sigf(z.y), gg = tanh_fast(z.z), og = sigf(z.w);
            float cn = fg * cv + ig * gg;
            c[gidx] = cn;
            h_out[gidx] = __float2bfloat16(og * tanh_fast(cn));
        }
    } else if (p_out) {
        // prediction tile: write p = h@W_d + b_d to output
        const int f0 = n0 - NG;
        for (int it = tid; it < 4096; it += 256) {
            int bl = it >> 6, fl = it & 63;
            p_out[(size_t)(b0 + bl) * (TFC * FEATS) + f0 + fl] = Zl[bl][fl];
        }
    }
}

// ---------- launcher ----------

extern "C" void kernel_launch(void* const* d_in, const int* in_sizes, int n_in,
                              void* d_out, int out_size, void* d_ws, size_t ws_size,
                              hipStream_t stream) {
    const float* inputs = (const float*)d_in[0];
    const float* W_i    = (const float*)d_in[1];
    const float* W_h    = (const float*)d_in[2];
    const float* b      = (const float*)d_in[3];
    const float* W_d    = (const float*)d_in[4];
    const float* b_d    = (const float*)d_in[5];
    float* out = (float*)d_out;

    char* ws = (char*)d_ws;
    // layout (bytes)
    __hip_bfloat16* x_bf   = (__hip_bfloat16*)(ws);                 // 16,777,216
    __hip_bfloat16* Wc     = (__hip_bfloat16*)(ws + 16777216);      //  9,437,184
    __hip_bfloat16* Wf     = (__hip_bfloat16*)(ws + 26214400);      //  8,650,752
    float*          bias_r = (float*)(ws + 34865152);               //     16,384
    float*          bias_f = (float*)(ws + 34881536);               //     16,896
    __hip_bfloat16* hbuf0  = (__hip_bfloat16*)(ws + 34898432);      //    524,288
    __hip_bfloat16* hbuf1  = (__hip_bfloat16*)(ws + 35422720);      //    524,288
    float*          cbuf   = (float*)(ws + 35947008);               //  1,048,576
    __hip_bfloat16* hb[2] = { hbuf0, hbuf1 };

    hipMemsetAsync(hbuf0, 0, 524288, stream);
    hipMemsetAsync(cbuf, 0, 1048576, stream);

    cvt_bf16<<<8192, 256, 0, stream>>>(inputs, x_bf, BATCH * TWARM * FEATS);
    build_wc<<<(NG * KW) / 256, 256, 0, stream>>>(W_h, W_i, Wc);
    build_wf<<<(NF * KF) / 256, 256, 0, stream>>>(W_h, W_i, W_d, Wf);
    build_bias<<<(NF + 255) / 256, 256, 0, stream>>>(b, b_d, W_i, bias_r, bias_f);

    // warmup: z = [h | x_t] @ [W_h; W_i]^T + b
    for (int t = 0; t < TWARM; ++t) {
        step_kernel<<<dim3(4, 64), 256, 0, stream>>>(
            Wc, bias_r, hb[t & 1], x_bf + (size_t)t * FEATS,
            cbuf, hb[(t + 1) & 1], nullptr, KW, TWARM * FEATS);
    }
    // forecast: z = h @ (W_h + W_d W_i)^T + (b + b_d W_i); p = h @ W_d + b_d -> out[:, t, :]
    for (int t = 0; t < TFC; ++t) {
        step_kernel<<<dim3(4, 66), 256, 0, stream>>>(
            Wf, bias_f, hb[t & 1], nullptr,
            cbuf, hb[(t + 1) & 1], out + (size_t)t * FEATS, KF, 0);
    }
}